// Round 1
// baseline (13643.855 us; speedup 1.0000x reference)
//
#include <hip/hip_runtime.h>

// ---------------- problem constants ----------------
constexpr int Bn = 128, Tn = 256, An = 16, Ln = 256, Sn = 32, Dn = 512, Hn = 512;
constexpr int STLD = 544;         // st row = [h(512), z(32)]
constexpr int GK   = 576;         // gates K padded: [h 512, z 32, a 16, pad 16]

typedef __bf16 bf16x8 __attribute__((ext_vector_type(8)));
typedef float  f32x4  __attribute__((ext_vector_type(4)));
typedef unsigned short u16;

__device__ __forceinline__ f32x4 mfma16(bf16x8 a, bf16x8 b, f32x4 c) {
  return __builtin_amdgcn_mfma_f32_16x16x32_bf16(a, b, c, 0, 0, 0);
}
__device__ __forceinline__ bf16x8 ld8(const u16* p) {
  return *reinterpret_cast<const bf16x8*>(p);
}
__device__ __forceinline__ f32x4 fz4() { f32x4 v = {0.f, 0.f, 0.f, 0.f}; return v; }
__device__ __forceinline__ u16 f2b(float f) {           // RNE f32 -> bf16 bits
  unsigned u = __float_as_uint(f);
  unsigned r = (u + 0x7fffu + ((u >> 16) & 1u)) >> 16;
  return (u16)r;
}
__device__ __forceinline__ float b2f(u16 x) { return __uint_as_float(((unsigned)x) << 16); }
__device__ __forceinline__ float sigm(float x) { return 1.f / (1.f + expf(-x)); }

// ---------------- weight / input conversion ----------------
__global__ void k_conv(const float* __restrict__ s, u16* __restrict__ d, int n) {
  int i = blockIdx.x * 256 + threadIdx.x;
  if (i < n) d[i] = f2b(s[i]);
}
// src [K][N] row-major f32  ->  dst[(n+nOff)*ld + kOff + k] bf16  (transposed)
__global__ void k_tconv(const float* __restrict__ s, u16* __restrict__ d,
                        int K, int N, int ld, int nOff, int kOff) {
  int i = blockIdx.x * 256 + threadIdx.x;
  if (i >= K * N) return;
  int k = i / N, n = i - k * N;
  d[(n + nOff) * ld + kOff + k] = f2b(s[i]);
}
__global__ void k_padWg(u16* __restrict__ d) {  // zero Wgt[:, 560:576]
  int i = blockIdx.x * 256 + threadIdx.x;
  if (i >= 1536 * 16) return;
  int n = i >> 4, j = i & 15;
  d[n * GK + 560 + j] = 0;
}

// ---------------- sequential step: posterior-sample (redundant) + GRU gates ----------------
__global__ __launch_bounds__(256) void k_step(
    int t,
    const u16* __restrict__ q1,          // [128][512] posterior hidden of t-1
    const u16* __restrict__ qW2t, const float* __restrict__ qb2,
    const float* __restrict__ eps, const float* __restrict__ z0,
    const float* __restrict__ h0, const u16* __restrict__ h0b,
    const u16* __restrict__ actb,        // [B][T][16]
    const u16* __restrict__ Wgt,         // [1536][576]
    const float* __restrict__ bih, const float* __restrict__ bhh,
    u16* __restrict__ st_all,            // [B*T][544]
    float* __restrict__ out_h, float* __restrict__ out_z,
    float* __restrict__ out_pmu, float* __restrict__ out_pls)
{
  __shared__ u16 zbuf[Bn * Sn];
  const int tid = threadIdx.x, lane = tid & 63, wv = tid >> 6;
  const int quad = lane >> 4, r16 = lane & 15;
  const int r0 = wv * 32 + r16, r1 = wv * 32 + 16 + r16;

  if (t == 0) {
    for (int i = tid; i < Bn * Sn; i += 256) zbuf[i] = f2b(z0[i]);
  } else {
    // posterior L2 (cols 0..63) + reparam sample, computed redundantly per block
    f32x4 acc[2][4];
#pragma unroll
    for (int a = 0; a < 2; ++a)
#pragma unroll
      for (int c = 0; c < 4; ++c) acc[a][c] = fz4();
    for (int kc = 0; kc < 16; ++kc) {
      const int k = kc * 32 + quad * 8;
      bf16x8 a0 = ld8(q1 + r0 * Hn + k);
      bf16x8 a1 = ld8(q1 + r1 * Hn + k);
#pragma unroll
      for (int cb = 0; cb < 4; ++cb) {
        bf16x8 bb = ld8(qW2t + (cb * 16 + r16) * Hn + k);
        acc[0][cb] = mfma16(a0, bb, acc[0][cb]);
        acc[1][cb] = mfma16(a1, bb, acc[1][cb]);
      }
    }
    const int tm1 = t - 1;
    const bool w0 = (blockIdx.x == 0);
#pragma unroll
    for (int rbi = 0; rbi < 2; ++rbi) {
      const int rowb = (wv * 2 + rbi) * 16 + quad * 4;
#pragma unroll
      for (int cb = 0; cb < 2; ++cb) {
        const int col = cb * 16 + r16;
#pragma unroll
        for (int i = 0; i < 4; ++i) {
          const int b = rowb + i;
          float mu = acc[rbi][cb][i] + qb2[col];
          float ls = acc[rbi][cb + 2][i] + qb2[col + 32];
          ls = fminf(fmaxf(ls, -10.f), 2.f);
          const float e = eps[(b * Tn + tm1) * Sn + col];
          const float z = mu + e * expf(ls);
          zbuf[b * Sn + col] = f2b(z);
          if (w0) {
            const int o = (b * Tn + tm1) * Sn + col;
            out_z[o] = z; out_pmu[o] = mu; out_pls[o] = ls;
            st_all[(b * Tn + tm1) * STLD + Dn + col] = f2b(z);
          }
        }
      }
    }
  }
  __syncthreads();

  // ---- GRU gates: h-cols j0..j0+31, gate cols {j0, 512+j0, 1024+j0} ----
  const u16* hsrc = (t == 0) ? h0b : (st_all + (t - 1) * STLD);
  const int  hstr = (t == 0) ? Dn : Tn * STLD;
  const int  j0 = blockIdx.x * 32;

  f32x4 aR[2][2], aU[2][2], aNi[2][2], aNh[2][2];
#pragma unroll
  for (int a = 0; a < 2; ++a)
#pragma unroll
    for (int c = 0; c < 2; ++c) { aR[a][c]=fz4(); aU[a][c]=fz4(); aNi[a][c]=fz4(); aNh[a][c]=fz4(); }

  for (int kc = 0; kc < 18; ++kc) {
    const int k = kc * 32 + quad * 8;
    bf16x8 a0, a1;
    if (kc < 16) {
      a0 = ld8(hsrc + r0 * hstr + k);
      a1 = ld8(hsrc + r1 * hstr + k);
    } else if (kc == 16) {
      a0 = ld8(&zbuf[r0 * Sn + (k - Dn)]);
      a1 = ld8(&zbuf[r1 * Sn + (k - Dn)]);
    } else {
      if (quad < 2) {
        a0 = ld8(actb + (r0 * Tn + t) * An + (k - 544));
        a1 = ld8(actb + (r1 * Tn + t) * An + (k - 544));
      } else {
        bf16x8 zz = {(__bf16)0.f,(__bf16)0.f,(__bf16)0.f,(__bf16)0.f,
                     (__bf16)0.f,(__bf16)0.f,(__bf16)0.f,(__bf16)0.f};
        a0 = zz; a1 = zz;
      }
    }
#pragma unroll
    for (int cb = 0; cb < 2; ++cb) {
      const int n = j0 + cb * 16 + r16;
      bf16x8 bR = ld8(Wgt + n * GK + k);
      bf16x8 bU = ld8(Wgt + (n + 512) * GK + k);
      bf16x8 bN = ld8(Wgt + (n + 1024) * GK + k);
      aR[0][cb] = mfma16(a0, bR, aR[0][cb]);
      aR[1][cb] = mfma16(a1, bR, aR[1][cb]);
      aU[0][cb] = mfma16(a0, bU, aU[0][cb]);
      aU[1][cb] = mfma16(a1, bU, aU[1][cb]);
      if (kc < 16) {
        aNh[0][cb] = mfma16(a0, bN, aNh[0][cb]);
        aNh[1][cb] = mfma16(a1, bN, aNh[1][cb]);
      } else {
        aNi[0][cb] = mfma16(a0, bN, aNi[0][cb]);
        aNi[1][cb] = mfma16(a1, bN, aNi[1][cb]);
      }
    }
  }

#pragma unroll
  for (int rbi = 0; rbi < 2; ++rbi) {
    const int rowb = (wv * 2 + rbi) * 16 + quad * 4;
#pragma unroll
    for (int cb = 0; cb < 2; ++cb) {
      const int ch = j0 + cb * 16 + r16;
      const float br  = bih[ch] + bhh[ch];
      const float bu  = bih[Dn + ch] + bhh[Dn + ch];
      const float bni = bih[2 * Dn + ch];
      const float bnh = bhh[2 * Dn + ch];
#pragma unroll
      for (int i = 0; i < 4; ++i) {
        const int b = rowb + i;
        const float r = sigm(aR[rbi][cb][i] + br);
        const float u = sigm(aU[rbi][cb][i] + bu);
        const float n = tanhf(aNi[rbi][cb][i] + bni + r * (aNh[rbi][cb][i] + bnh));
        const float hp = (t == 0) ? h0[b * Dn + ch]
                                  : out_h[(b * Tn + (t - 1)) * Dn + ch];
        const float hv = (1.f - u) * n + u * hp;
        out_h[(b * Tn + t) * Dn + ch] = hv;
        st_all[(b * Tn + t) * STLD + ch] = f2b(hv);
      }
    }
  }
}

// ---------------- posterior L1: q1 = relu([h_t, o_t] @ qW1 + qb1) ----------------
__global__ __launch_bounds__(256) void k_postl1(
    int t, const u16* __restrict__ st_all, const u16* __restrict__ obsb,
    const u16* __restrict__ qW1t, const float* __restrict__ qb1,
    u16* __restrict__ q1)
{
  const int tid = threadIdx.x, lane = tid & 63, wv = tid >> 6;
  const int quad = lane >> 4, r16 = lane & 15;
  const int n0 = blockIdx.x * 32;
  const int r0 = wv * 32 + r16, r1 = wv * 32 + 16 + r16;
  f32x4 acc[2][2];
#pragma unroll
  for (int a = 0; a < 2; ++a)
#pragma unroll
    for (int c = 0; c < 2; ++c) acc[a][c] = fz4();

  for (int kc = 0; kc < 24; ++kc) {
    const int k = kc * 32 + quad * 8;
    bf16x8 a0, a1;
    if (kc < 16) {
      a0 = ld8(st_all + (r0 * Tn + t) * STLD + k);
      a1 = ld8(st_all + (r1 * Tn + t) * STLD + k);
    } else {
      a0 = ld8(obsb + (r0 * Tn + t) * Ln + (k - Dn));
      a1 = ld8(obsb + (r1 * Tn + t) * Ln + (k - Dn));
    }
#pragma unroll
    for (int cb = 0; cb < 2; ++cb) {
      bf16x8 bb = ld8(qW1t + (n0 + cb * 16 + r16) * 768 + k);
      acc[0][cb] = mfma16(a0, bb, acc[0][cb]);
      acc[1][cb] = mfma16(a1, bb, acc[1][cb]);
    }
  }
#pragma unroll
  for (int rbi = 0; rbi < 2; ++rbi) {
    const int rowb = (wv * 2 + rbi) * 16 + quad * 4;
#pragma unroll
    for (int cb = 0; cb < 2; ++cb) {
      const int col = n0 + cb * 16 + r16;
      const float qb = qb1[col];
#pragma unroll
      for (int i = 0; i < 4; ++i) {
        float v = acc[rbi][cb][i] + qb;
        q1[(rowb + i) * Hn + col] = f2b(fmaxf(v, 0.f));
      }
    }
  }
}

// ---------------- final posterior sample for t = T-1 ----------------
__global__ __launch_bounds__(256) void k_post_sample(
    const u16* __restrict__ q1, const u16* __restrict__ qW2t,
    const float* __restrict__ qb2, const float* __restrict__ eps,
    u16* __restrict__ st_all,
    float* __restrict__ out_z, float* __restrict__ out_pmu, float* __restrict__ out_pls)
{
  const int tid = threadIdx.x, lane = tid & 63, wv = tid >> 6;
  const int quad = lane >> 4, r16 = lane & 15;
  const int r0 = wv * 32 + r16, r1 = wv * 32 + 16 + r16;
  f32x4 acc[2][4];
#pragma unroll
  for (int a = 0; a < 2; ++a)
#pragma unroll
    for (int c = 0; c < 4; ++c) acc[a][c] = fz4();
  for (int kc = 0; kc < 16; ++kc) {
    const int k = kc * 32 + quad * 8;
    bf16x8 a0 = ld8(q1 + r0 * Hn + k);
    bf16x8 a1 = ld8(q1 + r1 * Hn + k);
#pragma unroll
    for (int cb = 0; cb < 4; ++cb) {
      bf16x8 bb = ld8(qW2t + (cb * 16 + r16) * Hn + k);
      acc[0][cb] = mfma16(a0, bb, acc[0][cb]);
      acc[1][cb] = mfma16(a1, bb, acc[1][cb]);
    }
  }
  const int tm1 = Tn - 1;
#pragma unroll
  for (int rbi = 0; rbi < 2; ++rbi) {
    const int rowb = (wv * 2 + rbi) * 16 + quad * 4;
#pragma unroll
    for (int cb = 0; cb < 2; ++cb) {
      const int col = cb * 16 + r16;
#pragma unroll
      for (int i = 0; i < 4; ++i) {
        const int b = rowb + i;
        float mu = acc[rbi][cb][i] + qb2[col];
        float ls = acc[rbi][cb + 2][i] + qb2[col + 32];
        ls = fminf(fmaxf(ls, -10.f), 2.f);
        const float e = eps[(b * Tn + tm1) * Sn + col];
        const float z = mu + e * expf(ls);
        const int o = (b * Tn + tm1) * Sn + col;
        out_z[o] = z; out_pmu[o] = mu; out_pls[o] = ls;
        st_all[(b * Tn + tm1) * STLD + Dn + col] = f2b(z);
      }
    }
  }
}

// ---------------- batched prior MLP over all B*T rows ----------------
__global__ __launch_bounds__(256) void k_prior(
    const u16* __restrict__ st_all,
    const u16* __restrict__ pW1t, const float* __restrict__ pb1,
    const u16* __restrict__ pW2t, const float* __restrict__ pb2,
    float* __restrict__ out_pmu, float* __restrict__ out_pls)
{
  __shared__ u16 hid[64 * 512];
  const int tid = threadIdx.x, lane = tid & 63, wv = tid >> 6;
  const int quad = lane >> 4, r16 = lane & 15;
  const int m0 = blockIdx.x * 64;
  f32x4 acc[4][8];
#pragma unroll
  for (int a = 0; a < 4; ++a)
#pragma unroll
    for (int c = 0; c < 8; ++c) acc[a][c] = fz4();
  for (int kc = 0; kc < 16; ++kc) {
    const int k = kc * 32 + quad * 8;
    bf16x8 av[4];
#pragma unroll
    for (int rb = 0; rb < 4; ++rb)
      av[rb] = ld8(st_all + (m0 + rb * 16 + r16) * STLD + k);
#pragma unroll
    for (int cb = 0; cb < 8; ++cb) {
      bf16x8 bb = ld8(pW1t + (wv * 128 + cb * 16 + r16) * Dn + k);
#pragma unroll
      for (int rb = 0; rb < 4; ++rb) acc[rb][cb] = mfma16(av[rb], bb, acc[rb][cb]);
    }
  }
#pragma unroll
  for (int rb = 0; rb < 4; ++rb)
#pragma unroll
    for (int cb = 0; cb < 8; ++cb) {
      const int col = wv * 128 + cb * 16 + r16;
      const float pb = pb1[col];
#pragma unroll
      for (int i = 0; i < 4; ++i) {
        const int row = rb * 16 + quad * 4 + i;
        hid[row * 512 + ((col + row * 8) & 511)] = f2b(fmaxf(acc[rb][cb][i] + pb, 0.f));
      }
    }
  __syncthreads();
  f32x4 acc2[4];
#pragma unroll
  for (int rb = 0; rb < 4; ++rb) acc2[rb] = fz4();
  for (int kc = 0; kc < 16; ++kc) {
    const int k = kc * 32 + quad * 8;
    bf16x8 bb = ld8(pW2t + (wv * 16 + r16) * Dn + k);
#pragma unroll
    for (int rb = 0; rb < 4; ++rb) {
      const int row = rb * 16 + r16;
      bf16x8 aa = ld8(&hid[row * 512 + ((k + row * 8) & 511)]);
      acc2[rb] = mfma16(aa, bb, acc2[rb]);
    }
  }
  const int col = wv * 16 + r16;
#pragma unroll
  for (int rb = 0; rb < 4; ++rb)
#pragma unroll
    for (int i = 0; i < 4; ++i) {
      const int r = m0 + rb * 16 + quad * 4 + i;
      float v = acc2[rb][i] + pb2[col];
      if (col < Sn) out_pmu[r * Sn + col] = v;
      else out_pls[r * Sn + col - Sn] = fminf(fmaxf(v, -10.f), 2.f);
    }
}

// ---------------- batched obs head ----------------
__global__ __launch_bounds__(256) void k_obs(
    const u16* __restrict__ st_all, const u16* __restrict__ hW1t,
    const float* __restrict__ ob1, const u16* __restrict__ oW2t,
    const float* __restrict__ ob2, float* __restrict__ out_obs)
{
  __shared__ u16 hid[64 * 512];
  const int tid = threadIdx.x, lane = tid & 63, wv = tid >> 6;
  const int quad = lane >> 4, r16 = lane & 15;
  const int m0 = blockIdx.x * 64;
  f32x4 acc[4][8];
#pragma unroll
  for (int a = 0; a < 4; ++a)
#pragma unroll
    for (int c = 0; c < 8; ++c) acc[a][c] = fz4();
  for (int kc = 0; kc < 17; ++kc) {
    const int k = kc * 32 + quad * 8;
    bf16x8 av[4];
#pragma unroll
    for (int rb = 0; rb < 4; ++rb)
      av[rb] = ld8(st_all + (m0 + rb * 16 + r16) * STLD + k);
#pragma unroll
    for (int cb = 0; cb < 8; ++cb) {
      bf16x8 bb = ld8(hW1t + (wv * 128 + cb * 16 + r16) * STLD + k);
#pragma unroll
      for (int rb = 0; rb < 4; ++rb) acc[rb][cb] = mfma16(av[rb], bb, acc[rb][cb]);
    }
  }
#pragma unroll
  for (int rb = 0; rb < 4; ++rb)
#pragma unroll
    for (int cb = 0; cb < 8; ++cb) {
      const int col = wv * 128 + cb * 16 + r16;
      const float ob = ob1[col];
#pragma unroll
      for (int i = 0; i < 4; ++i) {
        const int row = rb * 16 + quad * 4 + i;
        hid[row * 512 + ((col + row * 8) & 511)] = f2b(fmaxf(acc[rb][cb][i] + ob, 0.f));
      }
    }
  __syncthreads();
  f32x4 acc2[4][4];
#pragma unroll
  for (int a = 0; a < 4; ++a)
#pragma unroll
    for (int c = 0; c < 4; ++c) acc2[a][c] = fz4();
  for (int kc = 0; kc < 16; ++kc) {
    const int k = kc * 32 + quad * 8;
    bf16x8 aa[4];
#pragma unroll
    for (int rb = 0; rb < 4; ++rb) {
      const int row = rb * 16 + r16;
      aa[rb] = ld8(&hid[row * 512 + ((k + row * 8) & 511)]);
    }
#pragma unroll
    for (int cb = 0; cb < 4; ++cb) {
      bf16x8 bb = ld8(oW2t + (wv * 64 + cb * 16 + r16) * Dn + k);
#pragma unroll
      for (int rb = 0; rb < 4; ++rb) acc2[rb][cb] = mfma16(aa[rb], bb, acc2[rb][cb]);
    }
  }
#pragma unroll
  for (int rb = 0; rb < 4; ++rb)
#pragma unroll
    for (int cb = 0; cb < 4; ++cb) {
      const int col = wv * 64 + cb * 16 + r16;
      const float ob = ob2[col];
#pragma unroll
      for (int i = 0; i < 4; ++i) {
        const int r = m0 + rb * 16 + quad * 4 + i;
        out_obs[r * Ln + col] = acc2[rb][cb][i] + ob;
      }
    }
}

// ---------------- batched reward + done heads ----------------
__global__ __launch_bounds__(256) void k_rewdone(
    const u16* __restrict__ st_all, const u16* __restrict__ hW1t,
    const float* __restrict__ rb1, const float* __restrict__ rW2, const float* __restrict__ rb2,
    const float* __restrict__ db1, const float* __restrict__ dW2, const float* __restrict__ db2,
    float* __restrict__ out_rew, float* __restrict__ out_done)
{
  __shared__ u16 hid[64 * 512];
  const int tid = threadIdx.x, lane = tid & 63, wv = tid >> 6;
  const int quad = lane >> 4, r16 = lane & 15;
  const int m0 = blockIdx.x * 64;

  for (int head = 0; head < 2; ++head) {
    const float* b1 = head ? db1 : rb1;
    const float* w2 = head ? dW2 : rW2;
    float* outp = head ? out_done : out_rew;
    const int nb = 512 + head * 512;

    f32x4 acc[4][8];
#pragma unroll
    for (int a = 0; a < 4; ++a)
#pragma unroll
      for (int c = 0; c < 8; ++c) acc[a][c] = fz4();
    for (int kc = 0; kc < 17; ++kc) {
      const int k = kc * 32 + quad * 8;
      bf16x8 av[4];
#pragma unroll
      for (int rb = 0; rb < 4; ++rb)
        av[rb] = ld8(st_all + (m0 + rb * 16 + r16) * STLD + k);
#pragma unroll
      for (int cb = 0; cb < 8; ++cb) {
        bf16x8 bb = ld8(hW1t + (nb + wv * 128 + cb * 16 + r16) * STLD + k);
#pragma unroll
        for (int rb = 0; rb < 4; ++rb) acc[rb][cb] = mfma16(av[rb], bb, acc[rb][cb]);
      }
    }
#pragma unroll
    for (int rb = 0; rb < 4; ++rb)
#pragma unroll
      for (int cb = 0; cb < 8; ++cb) {
        const int col = wv * 128 + cb * 16 + r16;
        const float bv = b1[col];
#pragma unroll
        for (int i = 0; i < 4; ++i) {
          const int row = rb * 16 + quad * 4 + i;
          hid[row * 512 + ((col + row * 8) & 511)] = f2b(fmaxf(acc[rb][cb][i] + bv, 0.f));
        }
      }
    __syncthreads();
    // dot with w2 (f32): 4 threads per row
    const int row = tid >> 2, part = tid & 3;
    float s = 0.f;
    for (int c = part * 128; c < part * 128 + 128; ++c)
      s += b2f(hid[row * 512 + ((c + row * 8) & 511)]) * w2[c];
    s += __shfl_xor(s, 1);
    s += __shfl_xor(s, 2);
    if (part == 0) outp[m0 + row] = s + (head ? db2[0] : rb2[0]);
    __syncthreads();
  }
}

// ---------------- host ----------------
extern "C" void kernel_launch(void* const* d_in, const int* in_sizes, int n_in,
                              void* d_out, int out_size, void* d_ws, size_t ws_size,
                              hipStream_t stream) {
  const float* actions = (const float*)d_in[0];
  const float* obs     = (const float*)d_in[1];
  const float* eps     = (const float*)d_in[2];
  const float* h0      = (const float*)d_in[3];
  const float* z0      = (const float*)d_in[4];
  const float* Wih     = (const float*)d_in[5];
  const float* Whh     = (const float*)d_in[6];
  const float* bih     = (const float*)d_in[7];
  const float* bhh     = (const float*)d_in[8];
  const float* pW1     = (const float*)d_in[9];
  const float* pb1     = (const float*)d_in[10];
  const float* pW2     = (const float*)d_in[11];
  const float* pb2     = (const float*)d_in[12];
  const float* qW1     = (const float*)d_in[13];
  const float* qb1     = (const float*)d_in[14];
  const float* qW2     = (const float*)d_in[15];
  const float* qb2     = (const float*)d_in[16];
  const float* oW1     = (const float*)d_in[17];
  const float* ob1     = (const float*)d_in[18];
  const float* oW2     = (const float*)d_in[19];
  const float* ob2     = (const float*)d_in[20];
  const float* rW1     = (const float*)d_in[21];
  const float* rb1     = (const float*)d_in[22];
  const float* rW2     = (const float*)d_in[23];
  const float* rb2     = (const float*)d_in[24];
  const float* dW1     = (const float*)d_in[25];
  const float* db1     = (const float*)d_in[26];
  const float* dW2     = (const float*)d_in[27];
  const float* db2     = (const float*)d_in[28];

  float* out = (float*)d_out;
  float* out_h    = out;                  // [B,T,512]
  float* out_z    = out + 16777216;       // [B,T,32]
  float* out_obs  = out + 17825792;       // [B,T,256]
  float* out_rew  = out + 26214400;       // [B,T]
  float* out_done = out + 26247168;       // [B,T]
  float* out_prmu = out + 26279936;       // [B,T,32]
  float* out_prls = out + 27328512;       // [B,T,32]
  float* out_pomu = out + 28377088;       // [B,T,32]
  float* out_pols = out + 29425664;       // [B,T,32]

  char* w = (char*)d_ws;
  u16* WGT  = (u16*)(w + 0);          // [1536][576]
  u16* QW1T = (u16*)(w + 1769472);    // [512][768]
  u16* QW2T = (u16*)(w + 2555904);    // [64][512]
  u16* PW1T = (u16*)(w + 2621440);    // [512][512]
  u16* PW2T = (u16*)(w + 3145728);    // [64][512]
  u16* HW1T = (u16*)(w + 3211264);    // [1536][544] (obs|rew|done)
  u16* OW2T = (u16*)(w + 4882432);    // [256][512]
  u16* H0B  = (u16*)(w + 5144576);    // [128][512]
  u16* ACTB = (u16*)(w + 5275648);    // [B][T][16]
  u16* OBSB = (u16*)(w + 6324224);    // [B][T][256]
  u16* STALL= (u16*)(w + 23101440);   // [B*T][544]
  u16* Q1   = (u16*)(w + 58753024);   // [128][512]

  auto nb = [](int n) { return dim3((unsigned)((n + 255) / 256)); };

  k_conv<<<nb(128 * 512), 256, 0, stream>>>(h0, H0B, 128 * 512);
  k_conv<<<nb(128 * 256 * 16), 256, 0, stream>>>(actions, ACTB, 128 * 256 * 16);
  k_conv<<<nb(128 * 256 * 256), 256, 0, stream>>>(obs, OBSB, 128 * 256 * 256);
  k_tconv<<<nb(512 * 1536), 256, 0, stream>>>(Whh, WGT, 512, 1536, GK, 0, 0);
  k_tconv<<<nb(48 * 1536), 256, 0, stream>>>(Wih, WGT, 48, 1536, GK, 0, 512);
  k_padWg<<<nb(1536 * 16), 256, 0, stream>>>(WGT);
  k_tconv<<<nb(768 * 512), 256, 0, stream>>>(qW1, QW1T, 768, 512, 768, 0, 0);
  k_tconv<<<nb(512 * 64), 256, 0, stream>>>(qW2, QW2T, 512, 64, 512, 0, 0);
  k_tconv<<<nb(512 * 512), 256, 0, stream>>>(pW1, PW1T, 512, 512, 512, 0, 0);
  k_tconv<<<nb(512 * 64), 256, 0, stream>>>(pW2, PW2T, 512, 64, 512, 0, 0);
  k_tconv<<<nb(544 * 512), 256, 0, stream>>>(oW1, HW1T, 544, 512, STLD, 0, 0);
  k_tconv<<<nb(544 * 512), 256, 0, stream>>>(rW1, HW1T, 544, 512, STLD, 512, 0);
  k_tconv<<<nb(544 * 512), 256, 0, stream>>>(dW1, HW1T, 544, 512, STLD, 1024, 0);
  k_tconv<<<nb(512 * 256), 256, 0, stream>>>(oW2, OW2T, 512, 256, 512, 0, 0);

  for (int t = 0; t < Tn; ++t) {
    k_step<<<16, 256, 0, stream>>>(t, Q1, QW2T, qb2, eps, z0, h0, H0B, ACTB, WGT,
                                   bih, bhh, STALL, out_h, out_z, out_pomu, out_pols);
    k_postl1<<<16, 256, 0, stream>>>(t, STALL, OBSB, QW1T, qb1, Q1);
  }
  k_post_sample<<<1, 256, 0, stream>>>(Q1, QW2T, qb2, eps, STALL, out_z, out_pomu, out_pols);

  k_prior<<<512, 256, 0, stream>>>(STALL, PW1T, pb1, PW2T, pb2, out_prmu, out_prls);
  k_obs<<<512, 256, 0, stream>>>(STALL, HW1T, ob1, OW2T, ob2, out_obs);
  k_rewdone<<<512, 256, 0, stream>>>(STALL, HW1T, rb1, rW2, rb2, db1, dW2, db2,
                                     out_rew, out_done);
}

// Round 3
// 10303.384 us; speedup vs baseline: 1.3242x; 1.3242x over previous
//
#include <hip/hip_runtime.h>

// ---------------- problem constants ----------------
constexpr int Bn = 128, Tn = 256, An = 16, Ln = 256, Sn = 32, Dn = 512, Hn = 512;
constexpr int STLD = 544;         // st row = [h(512), z(32)]
constexpr int GK   = 576;         // gates K padded: [h 512, z 32, a 16, pad 16]
constexpr int GRID = 64;          // persistent WGs (<= 256 CUs -> always co-resident)
constexpr int GWP  = 584;         // LDS gw row stride (conflict-free padding)

typedef __bf16 bf16x8 __attribute__((ext_vector_type(8)));
typedef float  f32x4  __attribute__((ext_vector_type(4)));
typedef unsigned short u16;

__device__ __forceinline__ f32x4 mfma16(bf16x8 a, bf16x8 b, f32x4 c) {
  return __builtin_amdgcn_mfma_f32_16x16x32_bf16(a, b, c, 0, 0, 0);
}
__device__ __forceinline__ bf16x8 ld8(const u16* p) {
  return *reinterpret_cast<const bf16x8*>(p);
}
__device__ __forceinline__ f32x4 fz4() { f32x4 v = {0.f, 0.f, 0.f, 0.f}; return v; }
__device__ __forceinline__ u16 f2b(float f) {           // RNE f32 -> bf16 bits
  unsigned u = __float_as_uint(f);
  unsigned r = (u + 0x7fffu + ((u >> 16) & 1u)) >> 16;
  return (u16)r;
}
__device__ __forceinline__ float b2f(u16 x) { return __uint_as_float(((unsigned)x) << 16); }
__device__ __forceinline__ float sigm(float x) { return 1.f / (1.f + expf(-x)); }

// ---------------- weight / input conversion ----------------
__global__ void k_conv(const float* __restrict__ s, u16* __restrict__ d, int n) {
  int i = blockIdx.x * 256 + threadIdx.x;
  if (i < n) d[i] = f2b(s[i]);
}
// src [K][N] row-major f32  ->  dst[(n+nOff)*ld + kOff + k] bf16  (transposed)
__global__ void k_tconv(const float* __restrict__ s, u16* __restrict__ d,
                        int K, int N, int ld, int nOff, int kOff) {
  int i = blockIdx.x * 256 + threadIdx.x;
  if (i >= K * N) return;
  int k = i / N, n = i - k * N;
  d[(n + nOff) * ld + kOff + k] = f2b(s[i]);
}
__global__ void k_padWg(u16* __restrict__ d) {  // zero Wgt[:, 560:576]
  int i = blockIdx.x * 256 + threadIdx.x;
  if (i >= 1536 * 16) return;
  int n = i >> 4, j = i & 15;
  d[n * GK + 560 + j] = 0;
}
__global__ void k_zero(unsigned* p) {
  if (blockIdx.x == 0 && threadIdx.x == 0) *p = 0u;
}

// ---------------- grid barrier (device-scope atomics; no coop launch needed) ----------------
__device__ __forceinline__ void gbar(unsigned* bar, unsigned& tgt) {
  __syncthreads();
  tgt += GRID;
  if (threadIdx.x == 0) {
    __threadfence();   // release: make this WG's global writes visible device-wide
    __hip_atomic_fetch_add(bar, 1u, __ATOMIC_RELEASE, __HIP_MEMORY_SCOPE_AGENT);
    while (__hip_atomic_load(bar, __ATOMIC_ACQUIRE, __HIP_MEMORY_SCOPE_AGENT) < tgt)
      __builtin_amdgcn_s_sleep(1);
  }
  __syncthreads();
  __threadfence();     // acquire: discard stale cached lines
}

// ---------------- persistent sequential kernel ----------------
struct SeqArgs {
  const u16* h0b;      // [128][512] bf16
  const u16* z0b;      // [128][32] bf16
  const float* h0;     // [128][512] f32
  const u16* actb;     // [B][T][16]
  const u16* obsb;     // [B][T][256]
  const float* eps;    // [B][T][32]
  const u16* Wgt;      // [1536][576]
  const float* bih; const float* bhh;
  const u16* qW1t;     // [512][768]
  const u16* qW2t;     // [64][512]
  const float* qb1; const float* qb2;
  u16* st_all;         // [B*T][544]
  u16* q1;             // [128][512]
  float* out_h; float* out_z; float* out_pomu; float* out_pols;
  unsigned* bar;
};

__global__ __launch_bounds__(256, 1) void k_seq(SeqArgs A) {
  __shared__ u16 gw[48 * GWP];
  const int tid = threadIdx.x, w = blockIdx.x;
  const int lane = tid & 63, wv = tid >> 6, quad = lane >> 4, r16 = lane & 15;
  const int cslice = (w & 31) * 16;     // 16-col slice (GRU h-cols & L1 cols)
  const int mh = w >> 5;                // M-half
  const int mrow0 = mh * 64 + wv * 16;  // this wave's 16 A-rows
  const bf16x8 z8 = {(__bf16)0.f,(__bf16)0.f,(__bf16)0.f,(__bf16)0.f,
                     (__bf16)0.f,(__bf16)0.f,(__bf16)0.f,(__bf16)0.f};

  // stage GRU weight slice into LDS: rows {r,u,n}x16cols, K=576 (pad to 584)
  for (int idx = tid; idx < 48 * 72; idx += 256) {
    int r = idx / 72, c = idx - r * 72;
    int g = r >> 4, rr = r & 15;
    const u16* src = A.Wgt + (g * 512 + cslice + rr) * GK + c * 8;
    *(uint4*)&gw[r * GWP + c * 8] = *(const uint4*)src;
  }
  // L1 weight frags -> registers (reused all 256 steps)
  bf16x8 lwreg[24];
#pragma unroll
  for (int kc = 0; kc < 24; ++kc)
    lwreg[kc] = ld8(A.qW1t + (cslice + r16) * 768 + kc * 32 + quad * 8);
  // qW2 frags -> registers (phase-C WGs, wave 0 only)
  bf16x8 qwm[16], qwl[16];
  const int mt = w >> 1, ntm = w & 1;
  if (w < 16 && wv == 0) {
#pragma unroll
    for (int kc = 0; kc < 16; ++kc) {
      qwm[kc] = ld8(A.qW2t + (ntm * 16 + r16) * 512 + kc * 32 + quad * 8);
      qwl[kc] = ld8(A.qW2t + (ntm * 16 + 32 + r16) * 512 + kc * 32 + quad * 8);
    }
  }
  // carried h (f32) for this lane's 4 (row,col) cells
  float hcar[4];
#pragma unroll
  for (int i = 0; i < 4; ++i)
    hcar[i] = A.h0[(mh * 64 + wv * 16 + quad * 4 + i) * Dn + cslice + r16];
  __syncthreads();

  unsigned tgt = 0;
  for (int t = 0; t < Tn; ++t) {
    // ================= phase A: GRU =================
    const u16* hP; long hS; const u16* zP; long zS;
    if (t == 0) { hP = A.h0b; hS = Dn; zP = A.z0b; zS = Sn; }
    else {
      hP = A.st_all + (long)(t - 1) * STLD; hS = (long)Tn * STLD;
      zP = hP + Dn; zS = hS;
    }
    f32x4 aR = fz4(), aU = fz4(), aNi = fz4(), aNh = fz4();
#pragma unroll
    for (int kc = 0; kc < 18; ++kc) {
      const int k = kc * 32 + quad * 8;
      bf16x8 a0;
      if (kc < 16)       a0 = ld8(hP + (long)(mrow0 + r16) * hS + k);
      else if (kc == 16) a0 = ld8(zP + (long)(mrow0 + r16) * zS + (k - Dn));
      else {
        if (quad < 2) a0 = ld8(A.actb + ((mrow0 + r16) * Tn + t) * An + (k - 544));
        else a0 = z8;
      }
      bf16x8 bR = ld8(&gw[r16 * GWP + k]);
      bf16x8 bU = ld8(&gw[(16 + r16) * GWP + k]);
      bf16x8 bN = ld8(&gw[(32 + r16) * GWP + k]);
      aR = mfma16(a0, bR, aR);
      aU = mfma16(a0, bU, aU);
      if (kc < 16) aNh = mfma16(a0, bN, aNh);
      else         aNi = mfma16(a0, bN, aNi);
    }
    {
      const int ch = cslice + r16;
      const float br  = A.bih[ch] + A.bhh[ch];
      const float bu  = A.bih[Dn + ch] + A.bhh[Dn + ch];
      const float bni = A.bih[2 * Dn + ch];
      const float bnh = A.bhh[2 * Dn + ch];
#pragma unroll
      for (int i = 0; i < 4; ++i) {
        const int b = mh * 64 + wv * 16 + quad * 4 + i;
        const float r = sigm(aR[i] + br);
        const float u = sigm(aU[i] + bu);
        const float n = tanhf(aNi[i] + bni + r * (aNh[i] + bnh));
        const float hv = (1.f - u) * n + u * hcar[i];
        hcar[i] = hv;
        A.out_h[((long)b * Tn + t) * Dn + ch] = hv;
        A.st_all[((long)b * Tn + t) * STLD + ch] = f2b(hv);
      }
    }
    gbar(A.bar, tgt);

    // ================= phase B: posterior L1 =================
    f32x4 q = fz4();
#pragma unroll
    for (int kc = 0; kc < 24; ++kc) {
      const int k = kc * 32 + quad * 8;
      bf16x8 a0 = (kc < 16)
        ? ld8(A.st_all + ((long)(mrow0 + r16) * Tn + t) * STLD + k)
        : ld8(A.obsb + ((mrow0 + r16) * Tn + t) * Ln + (k - Dn));
      q = mfma16(a0, lwreg[kc], q);
    }
    {
      const int col = cslice + r16;
      const float qb = A.qb1[col];
#pragma unroll
      for (int i = 0; i < 4; ++i) {
        const int b = mh * 64 + wv * 16 + quad * 4 + i;
        A.q1[b * Hn + col] = f2b(fmaxf(q[i] + qb, 0.f));
      }
    }
    gbar(A.bar, tgt);

    // ================= phase C: posterior L2 + sample =================
    if (w < 16 && wv == 0) {
      f32x4 am = fz4(), al = fz4();
#pragma unroll
      for (int kc = 0; kc < 16; ++kc) {
        const int k = kc * 32 + quad * 8;
        bf16x8 a0 = ld8(A.q1 + (mt * 16 + r16) * Hn + k);
        am = mfma16(a0, qwm[kc], am);
        al = mfma16(a0, qwl[kc], al);
      }
      const int col = ntm * 16 + r16;
      const float bm = A.qb2[col], bl = A.qb2[col + Sn];
#pragma unroll
      for (int i = 0; i < 4; ++i) {
        const int b = mt * 16 + quad * 4 + i;
        float mu = am[i] + bm;
        float ls = fminf(fmaxf(al[i] + bl, -10.f), 2.f);
        const float e = A.eps[((long)b * Tn + t) * Sn + col];
        const float z = mu + e * expf(ls);
        const long o = ((long)b * Tn + t) * Sn + col;
        A.out_z[o] = z; A.out_pomu[o] = mu; A.out_pols[o] = ls;
        A.st_all[((long)b * Tn + t) * STLD + Dn + col] = f2b(z);
      }
    }
    gbar(A.bar, tgt);
  }
}

// ---------------- batched prior MLP over all B*T rows ----------------
__global__ __launch_bounds__(256) void k_prior(
    const u16* __restrict__ st_all,
    const u16* __restrict__ pW1t, const float* __restrict__ pb1,
    const u16* __restrict__ pW2t, const float* __restrict__ pb2,
    float* __restrict__ out_pmu, float* __restrict__ out_pls)
{
  __shared__ u16 hid[64 * 512];
  const int tid = threadIdx.x, lane = tid & 63, wv = tid >> 6;
  const int quad = lane >> 4, r16 = lane & 15;
  const int m0 = blockIdx.x * 64;
  f32x4 acc[4][8];
#pragma unroll
  for (int a = 0; a < 4; ++a)
#pragma unroll
    for (int c = 0; c < 8; ++c) acc[a][c] = fz4();
  for (int kc = 0; kc < 16; ++kc) {
    const int k = kc * 32 + quad * 8;
    bf16x8 av[4];
#pragma unroll
    for (int rb = 0; rb < 4; ++rb)
      av[rb] = ld8(st_all + (m0 + rb * 16 + r16) * STLD + k);
#pragma unroll
    for (int cb = 0; cb < 8; ++cb) {
      bf16x8 bb = ld8(pW1t + (wv * 128 + cb * 16 + r16) * Dn + k);
#pragma unroll
      for (int rb = 0; rb < 4; ++rb) acc[rb][cb] = mfma16(av[rb], bb, acc[rb][cb]);
    }
  }
#pragma unroll
  for (int rb = 0; rb < 4; ++rb)
#pragma unroll
    for (int cb = 0; cb < 8; ++cb) {
      const int col = wv * 128 + cb * 16 + r16;
      const float pb = pb1[col];
#pragma unroll
      for (int i = 0; i < 4; ++i) {
        const int row = rb * 16 + quad * 4 + i;
        hid[row * 512 + ((col + row * 8) & 511)] = f2b(fmaxf(acc[rb][cb][i] + pb, 0.f));
      }
    }
  __syncthreads();
  f32x4 acc2[4];
#pragma unroll
  for (int rb = 0; rb < 4; ++rb) acc2[rb] = fz4();
  for (int kc = 0; kc < 16; ++kc) {
    const int k = kc * 32 + quad * 8;
    bf16x8 bb = ld8(pW2t + (wv * 16 + r16) * Dn + k);
#pragma unroll
    for (int rb = 0; rb < 4; ++rb) {
      const int row = rb * 16 + r16;
      bf16x8 aa = ld8(&hid[row * 512 + ((k + row * 8) & 511)]);
      acc2[rb] = mfma16(aa, bb, acc2[rb]);
    }
  }
  const int col = wv * 16 + r16;
#pragma unroll
  for (int rb = 0; rb < 4; ++rb)
#pragma unroll
    for (int i = 0; i < 4; ++i) {
      const int r = m0 + rb * 16 + quad * 4 + i;
      float v = acc2[rb][i] + pb2[col];
      if (col < Sn) out_pmu[r * Sn + col] = v;
      else out_pls[r * Sn + col - Sn] = fminf(fmaxf(v, -10.f), 2.f);
    }
}

// ---------------- batched obs head ----------------
__global__ __launch_bounds__(256) void k_obs(
    const u16* __restrict__ st_all, const u16* __restrict__ hW1t,
    const float* __restrict__ ob1, const u16* __restrict__ oW2t,
    const float* __restrict__ ob2, float* __restrict__ out_obs)
{
  __shared__ u16 hid[64 * 512];
  const int tid = threadIdx.x, lane = tid & 63, wv = tid >> 6;
  const int quad = lane >> 4, r16 = lane & 15;
  const int m0 = blockIdx.x * 64;
  f32x4 acc[4][8];
#pragma unroll
  for (int a = 0; a < 4; ++a)
#pragma unroll
    for (int c = 0; c < 8; ++c) acc[a][c] = fz4();
  for (int kc = 0; kc < 17; ++kc) {
    const int k = kc * 32 + quad * 8;
    bf16x8 av[4];
#pragma unroll
    for (int rb = 0; rb < 4; ++rb)
      av[rb] = ld8(st_all + (m0 + rb * 16 + r16) * STLD + k);
#pragma unroll
    for (int cb = 0; cb < 8; ++cb) {
      bf16x8 bb = ld8(hW1t + (wv * 128 + cb * 16 + r16) * STLD + k);
#pragma unroll
      for (int rb = 0; rb < 4; ++rb) acc[rb][cb] = mfma16(av[rb], bb, acc[rb][cb]);
    }
  }
#pragma unroll
  for (int rb = 0; rb < 4; ++rb)
#pragma unroll
    for (int cb = 0; cb < 8; ++cb) {
      const int col = wv * 128 + cb * 16 + r16;
      const float ob = ob1[col];
#pragma unroll
      for (int i = 0; i < 4; ++i) {
        const int row = rb * 16 + quad * 4 + i;
        hid[row * 512 + ((col + row * 8) & 511)] = f2b(fmaxf(acc[rb][cb][i] + ob, 0.f));
      }
    }
  __syncthreads();
  f32x4 acc2[4][4];
#pragma unroll
  for (int a = 0; a < 4; ++a)
#pragma unroll
    for (int c = 0; c < 4; ++c) acc2[a][c] = fz4();
  for (int kc = 0; kc < 16; ++kc) {
    const int k = kc * 32 + quad * 8;
    bf16x8 aa[4];
#pragma unroll
    for (int rb = 0; rb < 4; ++rb) {
      const int row = rb * 16 + r16;
      aa[rb] = ld8(&hid[row * 512 + ((k + row * 8) & 511)]);
    }
#pragma unroll
    for (int cb = 0; cb < 4; ++cb) {
      bf16x8 bb = ld8(oW2t + (wv * 64 + cb * 16 + r16) * Dn + k);
#pragma unroll
      for (int rb = 0; rb < 4; ++rb) acc2[rb][cb] = mfma16(aa[rb], bb, acc2[rb][cb]);
    }
  }
#pragma unroll
  for (int rb = 0; rb < 4; ++rb)
#pragma unroll
    for (int cb = 0; cb < 4; ++cb) {
      const int col = wv * 64 + cb * 16 + r16;
      const float ob = ob2[col];
#pragma unroll
      for (int i = 0; i < 4; ++i) {
        const int r = m0 + rb * 16 + quad * 4 + i;
        out_obs[r * Ln + col] = acc2[rb][cb][i] + ob;
      }
    }
}

// ---------------- batched reward + done heads ----------------
__global__ __launch_bounds__(256) void k_rewdone(
    const u16* __restrict__ st_all, const u16* __restrict__ hW1t,
    const float* __restrict__ rb1, const float* __restrict__ rW2, const float* __restrict__ rb2,
    const float* __restrict__ db1, const float* __restrict__ dW2, const float* __restrict__ db2,
    float* __restrict__ out_rew, float* __restrict__ out_done)
{
  __shared__ u16 hid[64 * 512];
  const int tid = threadIdx.x, lane = tid & 63, wv = tid >> 6;
  const int quad = lane >> 4, r16 = lane & 15;
  const int m0 = blockIdx.x * 64;

  for (int head = 0; head < 2; ++head) {
    const float* b1 = head ? db1 : rb1;
    const float* w2 = head ? dW2 : rW2;
    float* outp = head ? out_done : out_rew;
    const int nb = 512 + head * 512;

    f32x4 acc[4][8];
#pragma unroll
    for (int a = 0; a < 4; ++a)
#pragma unroll
      for (int c = 0; c < 8; ++c) acc[a][c] = fz4();
    for (int kc = 0; kc < 17; ++kc) {
      const int k = kc * 32 + quad * 8;
      bf16x8 av[4];
#pragma unroll
      for (int rb = 0; rb < 4; ++rb)
        av[rb] = ld8(st_all + (m0 + rb * 16 + r16) * STLD + k);
#pragma unroll
      for (int cb = 0; cb < 8; ++cb) {
        bf16x8 bb = ld8(hW1t + (nb + wv * 128 + cb * 16 + r16) * STLD + k);
#pragma unroll
        for (int rb = 0; rb < 4; ++rb) acc[rb][cb] = mfma16(av[rb], bb, acc[rb][cb]);
      }
    }
#pragma unroll
    for (int rb = 0; rb < 4; ++rb)
#pragma unroll
      for (int cb = 0; cb < 8; ++cb) {
        const int col = wv * 128 + cb * 16 + r16;
        const float bv = b1[col];
#pragma unroll
        for (int i = 0; i < 4; ++i) {
          const int row = rb * 16 + quad * 4 + i;
          hid[row * 512 + ((col + row * 8) & 511)] = f2b(fmaxf(acc[rb][cb][i] + bv, 0.f));
        }
      }
    __syncthreads();
    const int row = tid >> 2, part = tid & 3;
    float s = 0.f;
    for (int c = part * 128; c < part * 128 + 128; ++c)
      s += b2f(hid[row * 512 + ((c + row * 8) & 511)]) * w2[c];
    s += __shfl_xor(s, 1);
    s += __shfl_xor(s, 2);
    if (part == 0) outp[m0 + row] = s + (head ? db2[0] : rb2[0]);
    __syncthreads();
  }
}

// ---------------- host ----------------
extern "C" void kernel_launch(void* const* d_in, const int* in_sizes, int n_in,
                              void* d_out, int out_size, void* d_ws, size_t ws_size,
                              hipStream_t stream) {
  const float* actions = (const float*)d_in[0];
  const float* obs     = (const float*)d_in[1];
  const float* eps     = (const float*)d_in[2];
  const float* h0      = (const float*)d_in[3];
  const float* z0      = (const float*)d_in[4];
  const float* Wih     = (const float*)d_in[5];
  const float* Whh     = (const float*)d_in[6];
  const float* bih     = (const float*)d_in[7];
  const float* bhh     = (const float*)d_in[8];
  const float* pW1     = (const float*)d_in[9];
  const float* pb1     = (const float*)d_in[10];
  const float* pW2     = (const float*)d_in[11];
  const float* pb2     = (const float*)d_in[12];
  const float* qW1     = (const float*)d_in[13];
  const float* qb1     = (const float*)d_in[14];
  const float* qW2     = (const float*)d_in[15];
  const float* qb2     = (const float*)d_in[16];
  const float* oW1     = (const float*)d_in[17];
  const float* ob1     = (const float*)d_in[18];
  const float* oW2     = (const float*)d_in[19];
  const float* ob2     = (const float*)d_in[20];
  const float* rW1     = (const float*)d_in[21];
  const float* rb1     = (const float*)d_in[22];
  const float* rW2     = (const float*)d_in[23];
  const float* rb2     = (const float*)d_in[24];
  const float* dW1     = (const float*)d_in[25];
  const float* db1     = (const float*)d_in[26];
  const float* dW2     = (const float*)d_in[27];
  const float* db2     = (const float*)d_in[28];

  float* out = (float*)d_out;
  float* out_h    = out;                  // [B,T,512]
  float* out_z    = out + 16777216;       // [B,T,32]
  float* out_obs  = out + 17825792;       // [B,T,256]
  float* out_rew  = out + 26214400;       // [B,T]
  float* out_done = out + 26247168;       // [B,T]
  float* out_prmu = out + 26279936;       // [B,T,32]
  float* out_prls = out + 27328512;       // [B,T,32]
  float* out_pomu = out + 28377088;       // [B,T,32]
  float* out_pols = out + 29425664;       // [B,T,32]

  char* w = (char*)d_ws;
  u16* WGT  = (u16*)(w + 0);          // [1536][576]
  u16* QW1T = (u16*)(w + 1769472);    // [512][768]
  u16* QW2T = (u16*)(w + 2555904);    // [64][512]
  u16* PW1T = (u16*)(w + 2621440);    // [512][512]
  u16* PW2T = (u16*)(w + 3145728);    // [64][512]
  u16* HW1T = (u16*)(w + 3211264);    // [1536][544] (obs|rew|done)
  u16* OW2T = (u16*)(w + 4882432);    // [256][512]
  u16* H0B  = (u16*)(w + 5144576);    // [128][512]
  u16* ACTB = (u16*)(w + 5275648);    // [B][T][16]
  u16* OBSB = (u16*)(w + 6324224);    // [B][T][256]
  u16* STALL= (u16*)(w + 23101440);   // [B*T][544]
  u16* Q1   = (u16*)(w + 58753024);   // [128][512]
  u16* Z0B  = (u16*)(w + 58884096);   // [128][32]
  unsigned* BAR = (unsigned*)(w + 58892288);

  auto nb = [](int n) { return dim3((unsigned)((n + 255) / 256)); };

  k_zero<<<1, 64, 0, stream>>>(BAR);
  k_conv<<<nb(128 * 512), 256, 0, stream>>>(h0, H0B, 128 * 512);
  k_conv<<<nb(128 * 32), 256, 0, stream>>>(z0, Z0B, 128 * 32);
  k_conv<<<nb(128 * 256 * 16), 256, 0, stream>>>(actions, ACTB, 128 * 256 * 16);
  k_conv<<<nb(128 * 256 * 256), 256, 0, stream>>>(obs, OBSB, 128 * 256 * 256);
  k_tconv<<<nb(512 * 1536), 256, 0, stream>>>(Whh, WGT, 512, 1536, GK, 0, 0);
  k_tconv<<<nb(48 * 1536), 256, 0, stream>>>(Wih, WGT, 48, 1536, GK, 0, 512);
  k_padWg<<<nb(1536 * 16), 256, 0, stream>>>(WGT);
  k_tconv<<<nb(768 * 512), 256, 0, stream>>>(qW1, QW1T, 768, 512, 768, 0, 0);
  k_tconv<<<nb(512 * 64), 256, 0, stream>>>(qW2, QW2T, 512, 64, 512, 0, 0);
  k_tconv<<<nb(512 * 512), 256, 0, stream>>>(pW1, PW1T, 512, 512, 512, 0, 0);
  k_tconv<<<nb(512 * 64), 256, 0, stream>>>(pW2, PW2T, 512, 64, 512, 0, 0);
  k_tconv<<<nb(544 * 512), 256, 0, stream>>>(oW1, HW1T, 544, 512, STLD, 0, 0);
  k_tconv<<<nb(544 * 512), 256, 0, stream>>>(rW1, HW1T, 544, 512, STLD, 512, 0);
  k_tconv<<<nb(544 * 512), 256, 0, stream>>>(dW1, HW1T, 544, 512, STLD, 1024, 0);
  k_tconv<<<nb(512 * 256), 256, 0, stream>>>(oW2, OW2T, 512, 256, 512, 0, 0);

  SeqArgs sa;
  sa.h0b = H0B; sa.z0b = Z0B; sa.h0 = h0;
  sa.actb = ACTB; sa.obsb = OBSB; sa.eps = eps;
  sa.Wgt = WGT; sa.bih = bih; sa.bhh = bhh;
  sa.qW1t = QW1T; sa.qW2t = QW2T; sa.qb1 = qb1; sa.qb2 = qb2;
  sa.st_all = STALL; sa.q1 = Q1;
  sa.out_h = out_h; sa.out_z = out_z; sa.out_pomu = out_pomu; sa.out_pols = out_pols;
  sa.bar = BAR;
  // Plain launch: 64 blocks <= 256 CUs with __launch_bounds__(256,1) are always
  // co-resident; gbar() uses device-scope atomics so no cooperative launch needed.
  k_seq<<<dim3(GRID), dim3(256), 0, stream>>>(sa);

  k_prior<<<512, 256, 0, stream>>>(STALL, PW1T, pb1, PW2T, pb2, out_prmu, out_prls);
  k_obs<<<512, 256, 0, stream>>>(STALL, HW1T, ob1, OW2T, ob2, out_obs);
  k_rewdone<<<512, 256, 0, stream>>>(STALL, HW1T, rb1, rW2, rb2, db1, dW2, db2,
                                     out_rew, out_done);
}

// Round 4
// 7873.736 us; speedup vs baseline: 1.7328x; 1.3086x over previous
//
#include <hip/hip_runtime.h>

// ---------------- problem constants ----------------
constexpr int Bn = 128, Tn = 256, An = 16, Ln = 256, Sn = 32, Dn = 512, Hn = 512;
constexpr int STLD = 544;         // st row = [h(512), z(32)]
constexpr int GK   = 576;         // gates K padded: [h 512, z 32, a 16, pad 16]
constexpr int GRID = 64;          // persistent WGs (<= 256 CUs -> always co-resident)
constexpr int GWP  = 584;         // LDS gw row stride (conflict-free padding)

typedef __bf16 bf16x8 __attribute__((ext_vector_type(8)));
typedef float  f32x4  __attribute__((ext_vector_type(4)));
typedef unsigned short u16;

__device__ __forceinline__ f32x4 mfma16(bf16x8 a, bf16x8 b, f32x4 c) {
  return __builtin_amdgcn_mfma_f32_16x16x32_bf16(a, b, c, 0, 0, 0);
}
__device__ __forceinline__ bf16x8 ld8(const u16* p) {
  return *reinterpret_cast<const bf16x8*>(p);
}
__device__ __forceinline__ f32x4 fz4() { f32x4 v = {0.f, 0.f, 0.f, 0.f}; return v; }
__device__ __forceinline__ u16 f2b(float f) {           // RNE f32 -> bf16 bits
  unsigned u = __float_as_uint(f);
  unsigned r = (u + 0x7fffu + ((u >> 16) & 1u)) >> 16;
  return (u16)r;
}
__device__ __forceinline__ float b2f(u16 x) { return __uint_as_float(((unsigned)x) << 16); }
__device__ __forceinline__ float sigm(float x) { return 1.f / (1.f + expf(-x)); }

// ---------------- weight / input conversion ----------------
__global__ void k_conv(const float* __restrict__ s, u16* __restrict__ d, int n) {
  int i = blockIdx.x * 256 + threadIdx.x;
  if (i < n) d[i] = f2b(s[i]);
}
// src [K][N] row-major f32  ->  dst[(n+nOff)*ld + kOff + k] bf16  (transposed)
__global__ void k_tconv(const float* __restrict__ s, u16* __restrict__ d,
                        int K, int N, int ld, int nOff, int kOff) {
  int i = blockIdx.x * 256 + threadIdx.x;
  if (i >= K * N) return;
  int k = i / N, n = i - k * N;
  d[(n + nOff) * ld + kOff + k] = f2b(s[i]);
}
__global__ void k_padWg(u16* __restrict__ d) {  // zero Wgt[:, 560:576]
  int i = blockIdx.x * 256 + threadIdx.x;
  if (i >= 1536 * 16) return;
  int n = i >> 4, j = i & 15;
  d[n * GK + 560 + j] = 0;
}
__global__ void k_zero(unsigned* p) {
  if (blockIdx.x == 0 && threadIdx.x == 0) *p = 0u;
}

// ---------------- grid barrier (device-scope atomics; no coop launch needed) ----
// CRITICAL: poll with RELAXED. An ACQUIRE agent-scope load emits a cache
// invalidate per poll on gfx9-lineage -> 63 spinning WGs thrash all XCD L2s
// (round-3: 38us/step, MfmaUtil 0.35%). One acquire fence after the spin is
// sufficient (fence-fence synchronization with the RELEASE fetch_add).
__device__ __forceinline__ void gbar(unsigned* bar, unsigned& tgt) {
  __syncthreads();          // compiler emits vmcnt(0) drain before s_barrier
  tgt += GRID;
  if (threadIdx.x == 0) {
    __hip_atomic_fetch_add(bar, 1u, __ATOMIC_RELEASE, __HIP_MEMORY_SCOPE_AGENT);
    while (__hip_atomic_load(bar, __ATOMIC_RELAXED, __HIP_MEMORY_SCOPE_AGENT) < tgt)
      __builtin_amdgcn_s_sleep(2);
  }
  __syncthreads();
  __builtin_amdgcn_fence(__ATOMIC_ACQUIRE, "agent");  // one invalidate per barrier
}

// ---------------- persistent sequential kernel ----------------
struct SeqArgs {
  const u16* h0b;      // [128][512] bf16
  const u16* z0b;      // [128][32] bf16
  const float* h0;     // [128][512] f32
  const u16* actb;     // [B][T][16]
  const u16* obsb;     // [B][T][256]
  const float* eps;    // [B][T][32]
  const u16* Wgt;      // [1536][576]
  const float* bih; const float* bhh;
  const u16* qW1t;     // [512][768]
  const u16* qW2t;     // [64][512]
  const float* qb1; const float* qb2;
  u16* st_all;         // [B*T][544]
  u16* q1;             // [128][512]
  float* out_h; float* out_z; float* out_pomu; float* out_pols;
  unsigned* bar;
};

__global__ __launch_bounds__(256, 1) void k_seq(SeqArgs A) {
  __shared__ u16 gw[48 * GWP];
  const int tid = threadIdx.x, w = blockIdx.x;
  const int lane = tid & 63, wv = tid >> 6, quad = lane >> 4, r16 = lane & 15;
  const int cslice = (w & 31) * 16;     // 16-col slice (GRU h-cols & L1 cols)
  const int mh = w >> 5;                // M-half
  const int mrow0 = mh * 64 + wv * 16;  // this wave's 16 A-rows
  const bf16x8 z8 = {(__bf16)0.f,(__bf16)0.f,(__bf16)0.f,(__bf16)0.f,
                     (__bf16)0.f,(__bf16)0.f,(__bf16)0.f,(__bf16)0.f};

  // stage GRU weight slice into LDS: rows {r,u,n}x16cols, K=576 (pad to 584)
  for (int idx = tid; idx < 48 * 72; idx += 256) {
    int r = idx / 72, c = idx - r * 72;
    int g = r >> 4, rr = r & 15;
    const u16* src = A.Wgt + (g * 512 + cslice + rr) * GK + c * 8;
    *(uint4*)&gw[r * GWP + c * 8] = *(const uint4*)src;
  }
  // L1 weight frags -> registers (reused all 256 steps)
  bf16x8 lwreg[24];
#pragma unroll
  for (int kc = 0; kc < 24; ++kc)
    lwreg[kc] = ld8(A.qW1t + (cslice + r16) * 768 + kc * 32 + quad * 8);
  // qW2 frags -> registers (phase-C WGs, wave 0 only)
  bf16x8 qwm[16], qwl[16];
  const int mt = w >> 1, ntm = w & 1;
  if (w < 16 && wv == 0) {
#pragma unroll
    for (int kc = 0; kc < 16; ++kc) {
      qwm[kc] = ld8(A.qW2t + (ntm * 16 + r16) * 512 + kc * 32 + quad * 8);
      qwl[kc] = ld8(A.qW2t + (ntm * 16 + 32 + r16) * 512 + kc * 32 + quad * 8);
    }
  }
  // carried h (f32) for this lane's 4 (row,col) cells
  float hcar[4];
#pragma unroll
  for (int i = 0; i < 4; ++i)
    hcar[i] = A.h0[(mh * 64 + wv * 16 + quad * 4 + i) * Dn + cslice + r16];
  __syncthreads();

  unsigned tgt = 0;
  for (int t = 0; t < Tn; ++t) {
    // ================= phase A: GRU =================
    const u16* hP; long hS; const u16* zP; long zS;
    if (t == 0) { hP = A.h0b; hS = Dn; zP = A.z0b; zS = Sn; }
    else {
      hP = A.st_all + (long)(t - 1) * STLD; hS = (long)Tn * STLD;
      zP = hP + Dn; zS = hS;
    }
    f32x4 aR = fz4(), aU = fz4(), aNi = fz4(), aNh = fz4();
#pragma unroll
    for (int kc = 0; kc < 18; ++kc) {
      const int k = kc * 32 + quad * 8;
      bf16x8 a0;
      if (kc < 16)       a0 = ld8(hP + (long)(mrow0 + r16) * hS + k);
      else if (kc == 16) a0 = ld8(zP + (long)(mrow0 + r16) * zS + (k - Dn));
      else {
        if (quad < 2) a0 = ld8(A.actb + ((mrow0 + r16) * Tn + t) * An + (k - 544));
        else a0 = z8;
      }
      bf16x8 bR = ld8(&gw[r16 * GWP + k]);
      bf16x8 bU = ld8(&gw[(16 + r16) * GWP + k]);
      bf16x8 bN = ld8(&gw[(32 + r16) * GWP + k]);
      aR = mfma16(a0, bR, aR);
      aU = mfma16(a0, bU, aU);
      if (kc < 16) aNh = mfma16(a0, bN, aNh);
      else         aNi = mfma16(a0, bN, aNi);
    }
    {
      const int ch = cslice + r16;
      const float br  = A.bih[ch] + A.bhh[ch];
      const float bu  = A.bih[Dn + ch] + A.bhh[Dn + ch];
      const float bni = A.bih[2 * Dn + ch];
      const float bnh = A.bhh[2 * Dn + ch];
#pragma unroll
      for (int i = 0; i < 4; ++i) {
        const int b = mh * 64 + wv * 16 + quad * 4 + i;
        const float r = sigm(aR[i] + br);
        const float u = sigm(aU[i] + bu);
        const float n = tanhf(aNi[i] + bni + r * (aNh[i] + bnh));
        const float hv = (1.f - u) * n + u * hcar[i];
        hcar[i] = hv;
        A.out_h[((long)b * Tn + t) * Dn + ch] = hv;
        A.st_all[((long)b * Tn + t) * STLD + ch] = f2b(hv);
      }
    }
    gbar(A.bar, tgt);

    // ================= phase B: posterior L1 =================
    f32x4 q = fz4();
#pragma unroll
    for (int kc = 0; kc < 24; ++kc) {
      const int k = kc * 32 + quad * 8;
      bf16x8 a0 = (kc < 16)
        ? ld8(A.st_all + ((long)(mrow0 + r16) * Tn + t) * STLD + k)
        : ld8(A.obsb + ((mrow0 + r16) * Tn + t) * Ln + (k - Dn));
      q = mfma16(a0, lwreg[kc], q);
    }
    {
      const int col = cslice + r16;
      const float qb = A.qb1[col];
#pragma unroll
      for (int i = 0; i < 4; ++i) {
        const int b = mh * 64 + wv * 16 + quad * 4 + i;
        A.q1[b * Hn + col] = f2b(fmaxf(q[i] + qb, 0.f));
      }
    }
    gbar(A.bar, tgt);

    // ================= phase C: posterior L2 + sample =================
    if (w < 16 && wv == 0) {
      f32x4 am = fz4(), al = fz4();
#pragma unroll
      for (int kc = 0; kc < 16; ++kc) {
        const int k = kc * 32 + quad * 8;
        bf16x8 a0 = ld8(A.q1 + (mt * 16 + r16) * Hn + k);
        am = mfma16(a0, qwm[kc], am);
        al = mfma16(a0, qwl[kc], al);
      }
      const int col = ntm * 16 + r16;
      const float bm = A.qb2[col], bl = A.qb2[col + Sn];
#pragma unroll
      for (int i = 0; i < 4; ++i) {
        const int b = mt * 16 + quad * 4 + i;
        float mu = am[i] + bm;
        float ls = fminf(fmaxf(al[i] + bl, -10.f), 2.f);
        const float e = A.eps[((long)b * Tn + t) * Sn + col];
        const float z = mu + e * expf(ls);
        const long o = ((long)b * Tn + t) * Sn + col;
        A.out_z[o] = z; A.out_pomu[o] = mu; A.out_pols[o] = ls;
        A.st_all[((long)b * Tn + t) * STLD + Dn + col] = f2b(z);
      }
    }
    gbar(A.bar, tgt);
  }
}

// ---------------- batched prior MLP over all B*T rows ----------------
__global__ __launch_bounds__(256) void k_prior(
    const u16* __restrict__ st_all,
    const u16* __restrict__ pW1t, const float* __restrict__ pb1,
    const u16* __restrict__ pW2t, const float* __restrict__ pb2,
    float* __restrict__ out_pmu, float* __restrict__ out_pls)
{
  __shared__ u16 hid[64 * 512];
  const int tid = threadIdx.x, lane = tid & 63, wv = tid >> 6;
  const int quad = lane >> 4, r16 = lane & 15;
  const int m0 = blockIdx.x * 64;
  f32x4 acc[4][8];
#pragma unroll
  for (int a = 0; a < 4; ++a)
#pragma unroll
    for (int c = 0; c < 8; ++c) acc[a][c] = fz4();
  for (int kc = 0; kc < 16; ++kc) {
    const int k = kc * 32 + quad * 8;
    bf16x8 av[4];
#pragma unroll
    for (int rb = 0; rb < 4; ++rb)
      av[rb] = ld8(st_all + (m0 + rb * 16 + r16) * STLD + k);
#pragma unroll
    for (int cb = 0; cb < 8; ++cb) {
      bf16x8 bb = ld8(pW1t + (wv * 128 + cb * 16 + r16) * Dn + k);
#pragma unroll
      for (int rb = 0; rb < 4; ++rb) acc[rb][cb] = mfma16(av[rb], bb, acc[rb][cb]);
    }
  }
#pragma unroll
  for (int rb = 0; rb < 4; ++rb)
#pragma unroll
    for (int cb = 0; cb < 8; ++cb) {
      const int col = wv * 128 + cb * 16 + r16;
      const float pb = pb1[col];
#pragma unroll
      for (int i = 0; i < 4; ++i) {
        const int row = rb * 16 + quad * 4 + i;
        hid[row * 512 + ((col + row * 8) & 511)] = f2b(fmaxf(acc[rb][cb][i] + pb, 0.f));
      }
    }
  __syncthreads();
  f32x4 acc2[4];
#pragma unroll
  for (int rb = 0; rb < 4; ++rb) acc2[rb] = fz4();
  for (int kc = 0; kc < 16; ++kc) {
    const int k = kc * 32 + quad * 8;
    bf16x8 bb = ld8(pW2t + (wv * 16 + r16) * Dn + k);
#pragma unroll
    for (int rb = 0; rb < 4; ++rb) {
      const int row = rb * 16 + r16;
      bf16x8 aa = ld8(&hid[row * 512 + ((k + row * 8) & 511)]);
      acc2[rb] = mfma16(aa, bb, acc2[rb]);
    }
  }
  const int col = wv * 16 + r16;
#pragma unroll
  for (int rb = 0; rb < 4; ++rb)
#pragma unroll
    for (int i = 0; i < 4; ++i) {
      const int r = m0 + rb * 16 + quad * 4 + i;
      float v = acc2[rb][i] + pb2[col];
      if (col < Sn) out_pmu[r * Sn + col] = v;
      else out_pls[r * Sn + col - Sn] = fminf(fmaxf(v, -10.f), 2.f);
    }
}

// ---------------- batched obs head ----------------
__global__ __launch_bounds__(256) void k_obs(
    const u16* __restrict__ st_all, const u16* __restrict__ hW1t,
    const float* __restrict__ ob1, const u16* __restrict__ oW2t,
    const float* __restrict__ ob2, float* __restrict__ out_obs)
{
  __shared__ u16 hid[64 * 512];
  const int tid = threadIdx.x, lane = tid & 63, wv = tid >> 6;
  const int quad = lane >> 4, r16 = lane & 15;
  const int m0 = blockIdx.x * 64;
  f32x4 acc[4][8];
#pragma unroll
  for (int a = 0; a < 4; ++a)
#pragma unroll
    for (int c = 0; c < 8; ++c) acc[a][c] = fz4();
  for (int kc = 0; kc < 17; ++kc) {
    const int k = kc * 32 + quad * 8;
    bf16x8 av[4];
#pragma unroll
    for (int rb = 0; rb < 4; ++rb)
      av[rb] = ld8(st_all + (m0 + rb * 16 + r16) * STLD + k);
#pragma unroll
    for (int cb = 0; cb < 8; ++cb) {
      bf16x8 bb = ld8(hW1t + (wv * 128 + cb * 16 + r16) * STLD + k);
#pragma unroll
      for (int rb = 0; rb < 4; ++rb) acc[rb][cb] = mfma16(av[rb], bb, acc[rb][cb]);
    }
  }
#pragma unroll
  for (int rb = 0; rb < 4; ++rb)
#pragma unroll
    for (int cb = 0; cb < 8; ++cb) {
      const int col = wv * 128 + cb * 16 + r16;
      const float ob = ob1[col];
#pragma unroll
      for (int i = 0; i < 4; ++i) {
        const int row = rb * 16 + quad * 4 + i;
        hid[row * 512 + ((col + row * 8) & 511)] = f2b(fmaxf(acc[rb][cb][i] + ob, 0.f));
      }
    }
  __syncthreads();
  f32x4 acc2[4][4];
#pragma unroll
  for (int a = 0; a < 4; ++a)
#pragma unroll
    for (int c = 0; c < 4; ++c) acc2[a][c] = fz4();
  for (int kc = 0; kc < 16; ++kc) {
    const int k = kc * 32 + quad * 8;
    bf16x8 aa[4];
#pragma unroll
    for (int rb = 0; rb < 4; ++rb) {
      const int row = rb * 16 + r16;
      aa[rb] = ld8(&hid[row * 512 + ((k + row * 8) & 511)]);
    }
#pragma unroll
    for (int cb = 0; cb < 4; ++cb) {
      bf16x8 bb = ld8(oW2t + (wv * 64 + cb * 16 + r16) * Dn + k);
#pragma unroll
      for (int rb = 0; rb < 4; ++rb) acc2[rb][cb] = mfma16(aa[rb], bb, acc2[rb][cb]);
    }
  }
#pragma unroll
  for (int rb = 0; rb < 4; ++rb)
#pragma unroll
    for (int cb = 0; cb < 4; ++cb) {
      const int col = wv * 64 + cb * 16 + r16;
      const float ob = ob2[col];
#pragma unroll
      for (int i = 0; i < 4; ++i) {
        const int r = m0 + rb * 16 + quad * 4 + i;
        out_obs[r * Ln + col] = acc2[rb][cb][i] + ob;
      }
    }
}

// ---------------- batched reward + done heads ----------------
__global__ __launch_bounds__(256) void k_rewdone(
    const u16* __restrict__ st_all, const u16* __restrict__ hW1t,
    const float* __restrict__ rb1, const float* __restrict__ rW2, const float* __restrict__ rb2,
    const float* __restrict__ db1, const float* __restrict__ dW2, const float* __restrict__ db2,
    float* __restrict__ out_rew, float* __restrict__ out_done)
{
  __shared__ u16 hid[64 * 512];
  const int tid = threadIdx.x, lane = tid & 63, wv = tid >> 6;
  const int quad = lane >> 4, r16 = lane & 15;
  const int m0 = blockIdx.x * 64;

  for (int head = 0; head < 2; ++head) {
    const float* b1 = head ? db1 : rb1;
    const float* w2 = head ? dW2 : rW2;
    float* outp = head ? out_done : out_rew;
    const int nb = 512 + head * 512;

    f32x4 acc[4][8];
#pragma unroll
    for (int a = 0; a < 4; ++a)
#pragma unroll
      for (int c = 0; c < 8; ++c) acc[a][c] = fz4();
    for (int kc = 0; kc < 17; ++kc) {
      const int k = kc * 32 + quad * 8;
      bf16x8 av[4];
#pragma unroll
      for (int rb = 0; rb < 4; ++rb)
        av[rb] = ld8(st_all + (m0 + rb * 16 + r16) * STLD + k);
#pragma unroll
      for (int cb = 0; cb < 8; ++cb) {
        bf16x8 bb = ld8(hW1t + (nb + wv * 128 + cb * 16 + r16) * STLD + k);
#pragma unroll
        for (int rb = 0; rb < 4; ++rb) acc[rb][cb] = mfma16(av[rb], bb, acc[rb][cb]);
      }
    }
#pragma unroll
    for (int rb = 0; rb < 4; ++rb)
#pragma unroll
      for (int cb = 0; cb < 8; ++cb) {
        const int col = wv * 128 + cb * 16 + r16;
        const float bv = b1[col];
#pragma unroll
        for (int i = 0; i < 4; ++i) {
          const int row = rb * 16 + quad * 4 + i;
          hid[row * 512 + ((col + row * 8) & 511)] = f2b(fmaxf(acc[rb][cb][i] + bv, 0.f));
        }
      }
    __syncthreads();
    const int row = tid >> 2, part = tid & 3;
    float s = 0.f;
    for (int c = part * 128; c < part * 128 + 128; ++c)
      s += b2f(hid[row * 512 + ((c + row * 8) & 511)]) * w2[c];
    s += __shfl_xor(s, 1);
    s += __shfl_xor(s, 2);
    if (part == 0) outp[m0 + row] = s + (head ? db2[0] : rb2[0]);
    __syncthreads();
  }
}

// ---------------- host ----------------
extern "C" void kernel_launch(void* const* d_in, const int* in_sizes, int n_in,
                              void* d_out, int out_size, void* d_ws, size_t ws_size,
                              hipStream_t stream) {
  const float* actions = (const float*)d_in[0];
  const float* obs     = (const float*)d_in[1];
  const float* eps     = (const float*)d_in[2];
  const float* h0      = (const float*)d_in[3];
  const float* z0      = (const float*)d_in[4];
  const float* Wih     = (const float*)d_in[5];
  const float* Whh     = (const float*)d_in[6];
  const float* bih     = (const float*)d_in[7];
  const float* bhh     = (const float*)d_in[8];
  const float* pW1     = (const float*)d_in[9];
  const float* pb1     = (const float*)d_in[10];
  const float* pW2     = (const float*)d_in[11];
  const float* pb2     = (const float*)d_in[12];
  const float* qW1     = (const float*)d_in[13];
  const float* qb1     = (const float*)d_in[14];
  const float* qW2     = (const float*)d_in[15];
  const float* qb2     = (const float*)d_in[16];
  const float* oW1     = (const float*)d_in[17];
  const float* ob1     = (const float*)d_in[18];
  const float* oW2     = (const float*)d_in[19];
  const float* ob2     = (const float*)d_in[20];
  const float* rW1     = (const float*)d_in[21];
  const float* rb1     = (const float*)d_in[22];
  const float* rW2     = (const float*)d_in[23];
  const float* rb2     = (const float*)d_in[24];
  const float* dW1     = (const float*)d_in[25];
  const float* db1     = (const float*)d_in[26];
  const float* dW2     = (const float*)d_in[27];
  const float* db2     = (const float*)d_in[28];

  float* out = (float*)d_out;
  float* out_h    = out;                  // [B,T,512]
  float* out_z    = out + 16777216;       // [B,T,32]
  float* out_obs  = out + 17825792;       // [B,T,256]
  float* out_rew  = out + 26214400;       // [B,T]
  float* out_done = out + 26247168;       // [B,T]
  float* out_prmu = out + 26279936;       // [B,T,32]
  float* out_prls = out + 27328512;       // [B,T,32]
  float* out_pomu = out + 28377088;       // [B,T,32]
  float* out_pols = out + 29425664;       // [B,T,32]

  char* w = (char*)d_ws;
  u16* WGT  = (u16*)(w + 0);          // [1536][576]
  u16* QW1T = (u16*)(w + 1769472);    // [512][768]
  u16* QW2T = (u16*)(w + 2555904);    // [64][512]
  u16* PW1T = (u16*)(w + 2621440);    // [512][512]
  u16* PW2T = (u16*)(w + 3145728);    // [64][512]
  u16* HW1T = (u16*)(w + 3211264);    // [1536][544] (obs|rew|done)
  u16* OW2T = (u16*)(w + 4882432);    // [256][512]
  u16* H0B  = (u16*)(w + 5144576);    // [128][512]
  u16* ACTB = (u16*)(w + 5275648);    // [B][T][16]
  u16* OBSB = (u16*)(w + 6324224);    // [B][T][256]
  u16* STALL= (u16*)(w + 23101440);   // [B*T][544]
  u16* Q1   = (u16*)(w + 58753024);   // [128][512]
  u16* Z0B  = (u16*)(w + 58884096);   // [128][32]
  unsigned* BAR = (unsigned*)(w + 58892288);

  auto nb = [](int n) { return dim3((unsigned)((n + 255) / 256)); };

  k_zero<<<1, 64, 0, stream>>>(BAR);
  k_conv<<<nb(128 * 512), 256, 0, stream>>>(h0, H0B, 128 * 512);
  k_conv<<<nb(128 * 32), 256, 0, stream>>>(z0, Z0B, 128 * 32);
  k_conv<<<nb(128 * 256 * 16), 256, 0, stream>>>(actions, ACTB, 128 * 256 * 16);
  k_conv<<<nb(128 * 256 * 256), 256, 0, stream>>>(obs, OBSB, 128 * 256 * 256);
  k_tconv<<<nb(512 * 1536), 256, 0, stream>>>(Whh, WGT, 512, 1536, GK, 0, 0);
  k_tconv<<<nb(48 * 1536), 256, 0, stream>>>(Wih, WGT, 48, 1536, GK, 0, 512);
  k_padWg<<<nb(1536 * 16), 256, 0, stream>>>(WGT);
  k_tconv<<<nb(768 * 512), 256, 0, stream>>>(qW1, QW1T, 768, 512, 768, 0, 0);
  k_tconv<<<nb(512 * 64), 256, 0, stream>>>(qW2, QW2T, 512, 64, 512, 0, 0);
  k_tconv<<<nb(512 * 512), 256, 0, stream>>>(pW1, PW1T, 512, 512, 512, 0, 0);
  k_tconv<<<nb(512 * 64), 256, 0, stream>>>(pW2, PW2T, 512, 64, 512, 0, 0);
  k_tconv<<<nb(544 * 512), 256, 0, stream>>>(oW1, HW1T, 544, 512, STLD, 0, 0);
  k_tconv<<<nb(544 * 512), 256, 0, stream>>>(rW1, HW1T, 544, 512, STLD, 512, 0);
  k_tconv<<<nb(544 * 512), 256, 0, stream>>>(dW1, HW1T, 544, 512, STLD, 1024, 0);
  k_tconv<<<nb(512 * 256), 256, 0, stream>>>(oW2, OW2T, 512, 256, 512, 0, 0);

  SeqArgs sa;
  sa.h0b = H0B; sa.z0b = Z0B; sa.h0 = h0;
  sa.actb = ACTB; sa.obsb = OBSB; sa.eps = eps;
  sa.Wgt = WGT; sa.bih = bih; sa.bhh = bhh;
  sa.qW1t = QW1T; sa.qW2t = QW2T; sa.qb1 = qb1; sa.qb2 = qb2;
  sa.st_all = STALL; sa.q1 = Q1;
  sa.out_h = out_h; sa.out_z = out_z; sa.out_pomu = out_pomu; sa.out_pols = out_pols;
  sa.bar = BAR;
  k_seq<<<dim3(GRID), dim3(256), 0, stream>>>(sa);

  k_prior<<<512, 256, 0, stream>>>(STALL, PW1T, pb1, PW2T, pb2, out_prmu, out_prls);
  k_obs<<<512, 256, 0, stream>>>(STALL, HW1T, ob1, OW2T, ob2, out_obs);
  k_rewdone<<<512, 256, 0, stream>>>(STALL, HW1T, rb1, rW2, rb2, db1, dW2, db2,
                                     out_rew, out_done);
}